// Round 9
// baseline (485.425 us; speedup 1.0000x reference)
//
#include <hip/hip_runtime.h>

// HypergraphModel on MI355X.
// R9: (1) k_bucket 4096 pins/block — halves partial-line write amp (R8: 48 MB
//     written vs 12.8 logical) and reserve-atomics; (2) seg_agg 8-wide pin
//     unroll (2x memory-level parallelism in the latency-bound gather);
//     (3) k_gemm_lv + k_decode fused into k_lv_dec (one a3 pass: lv row per
//     16-lane group + composed decode spread across lanes, shfl-reduced).
//     Else = R8 (counting-sort CSR, bf16 gathers, composed mu elimination).

#define NN 100000
#define NE 100000
#define NP 1600000
#define NBK  391   // buckets per side (256 ids each); NBK*256 = 100,096
#define BCAP 4608  // bucket cap (mean 4096, +8 sigma)
#define CCAP 48    // padded CSR row stride (Poisson(16) + >8 sigma)

// ws offsets in 4-byte words (sizes in words) — non-overlapping:
#define O_GCURE 0              // 512  (zeroed)
#define O_GCURN 512            // 512  (zeroed)
#define O_NORM  1024           // 64   (zeroed)
#define O_DEGE  1088           // 100,000
#define O_DEGN  101088         // 100,000
#define O_BINV  201088         // 100,000
#define O_DINV  301088         // 100,000
#define O_BKTE  401088         // NBK*BCAP = 1,801,728
#define O_BKTN  2202816        // 1,801,728
#define O_CSRE  4004544        // NE*CCAP = 4,800,000
#define O_CSRN  8804544        // 4,800,000
#define O_XB    13604544       // bf16 100000x32 = 1,600,000 words
#define O_T     15204544       // bf16 100000x64 = 3,200,000 words
#define O_HE    18404544       // bf16 100000x64 = 3,200,000 words
#define O_A     21604544       // fp32 100000x64 = 6,400,000 words
#define O_C1    28004544       // fp32 64x32 = 2,048 (composed Wmu@dW1)
#define O_C1B   28006592       // fp32 32 (composed bias)
// end 28,006,624 words = 112 MB

typedef unsigned int uint32;

__device__ __forceinline__ float b2f_lo(uint32 u) { return __uint_as_float(u << 16); }
__device__ __forceinline__ float b2f_hi(uint32 u) { return __uint_as_float(u & 0xFFFF0000u); }
__device__ __forceinline__ uint32 f2b(float f) {  // RNE fp32 -> bf16
  uint32 b = __float_as_uint(f);
  return (b + 0x7FFFu + ((b >> 16) & 1u)) >> 16;
}
__device__ __forceinline__ uint32 pack2(float lo, float hi) {
  return f2b(lo) | (f2b(hi) << 16);
}

// ---- Pass A: bucketize pins (4096 pins/block, 16/thread).
__global__ __launch_bounds__(256) void k_bucket(const int* __restrict__ nidx,
                                                const int* __restrict__ eidx,
                                                int* __restrict__ gcurE,
                                                int* __restrict__ gcurN,
                                                int* __restrict__ bktE,
                                                int* __restrict__ bktN) {
  __shared__ int cntE[NBK], cntN[NBK], curE[NBK], curN[NBK];
  for (int i = threadIdx.x; i < NBK; i += 256) { cntE[i] = 0; cntN[i] = 0; }
  __syncthreads();
  int base = blockIdx.x * 4096 + threadIdx.x * 16;
  int n[16], e[16];
  int cnt = 0;
  if (base + 16 <= NP) {
#pragma unroll
    for (int q = 0; q < 4; ++q) {
      int4 a = *(const int4*)(nidx + base + 4 * q);
      int4 b = *(const int4*)(eidx + base + 4 * q);
      n[4 * q + 0] = a.x; n[4 * q + 1] = a.y; n[4 * q + 2] = a.z; n[4 * q + 3] = a.w;
      e[4 * q + 0] = b.x; e[4 * q + 1] = b.y; e[4 * q + 2] = b.z; e[4 * q + 3] = b.w;
    }
    cnt = 16;
  } else {
    for (int i = 0; i < 16 && base + i < NP; ++i) {
      n[i] = nidx[base + i];
      e[i] = eidx[base + i];
      ++cnt;
    }
  }
  for (int i = 0; i < cnt; ++i) {
    atomicAdd(&cntE[e[i] >> 8], 1);
    atomicAdd(&cntN[n[i] >> 8], 1);
  }
  __syncthreads();
  for (int i = threadIdx.x; i < NBK; i += 256) {
    curE[i] = atomicAdd(&gcurE[i], cntE[i]);
    curN[i] = atomicAdd(&gcurN[i], cntN[i]);
  }
  __syncthreads();
  for (int i = 0; i < cnt; ++i) {
    int be = e[i] >> 8, bn = n[i] >> 8;
    int se = atomicAdd(&curE[be], 1);
    if (se < BCAP) bktE[be * BCAP + se] = ((e[i] & 255) << 24) | n[i];
    int sn = atomicAdd(&curN[bn], 1);
    if (sn < BCAP) bktN[bn * BCAP + sn] = ((n[i] & 255) << 24) | e[i];
  }
}

// ---- Pass B: per-bucket padded-CSR build + deg + 1/deg (LDS atomics only).
__global__ __launch_bounds__(256) void k_csr2(const int* __restrict__ gcurE,
                                              const int* __restrict__ gcurN,
                                              const int* __restrict__ bktE,
                                              const int* __restrict__ bktN,
                                              int* __restrict__ csrE,
                                              int* __restrict__ csrN,
                                              int* __restrict__ degE,
                                              int* __restrict__ degN,
                                              float* __restrict__ invE,
                                              float* __restrict__ invN) {
  int bb = blockIdx.x;
  bool es = bb < NBK;
  int b = es ? bb : bb - NBK;
  const int* gcur = es ? gcurE : gcurN;
  const int* bkt  = es ? bktE : bktN;
  int*   csr = es ? csrE : csrN;
  int*   deg = es ? degE : degN;
  float* inv = es ? invE : invN;

  __shared__ int ent[BCAP];
  __shared__ int cnt[256], cur[256];
  int m = gcur[b];
  if (m > BCAP) m = BCAP;
  for (int i = threadIdx.x; i < m; i += 256) ent[i] = bkt[b * BCAP + i];
  cnt[threadIdx.x] = 0;
  __syncthreads();
  for (int i = threadIdx.x; i < m; i += 256)
    atomicAdd(&cnt[((unsigned)ent[i]) >> 24], 1);
  __syncthreads();
  int id = (b << 8) + threadIdx.x;
  if (id < NN) {  // NN == NE
    int d = cnt[threadIdx.x];
    deg[id] = d < CCAP ? d : CCAP;
    inv[id] = d > 0 ? 1.0f / (float)d : 0.0f;
  }
  cur[threadIdx.x] = 0;
  __syncthreads();
  for (int i = threadIdx.x; i < m; i += 256) {
    unsigned v = (unsigned)ent[i];
    int loc = v >> 24;
    int payload = v & 0xFFFFFF;
    int slot = atomicAdd(&cur[loc], 1);
    if (slot < CCAP) csr[(long)((b << 8) + loc) * CCAP + slot] = payload;
  }
}

// Compose decode layer1 with the mu head: C1 = Wmu@dW1, c1 = bmu@dW1 + db1.
__global__ __launch_bounds__(256) void k_compose(const float* __restrict__ Wmu,
                                                 const float* __restrict__ bmu,
                                                 const float* __restrict__ dW1,
                                                 const float* __restrict__ db1,
                                                 float* __restrict__ C1,
                                                 float* __restrict__ c1) {
  int t = threadIdx.x;
  for (int idx = t; idx < 64 * 32; idx += 256) {
    int i = idx >> 5, j = idx & 31;
    float s = 0.f;
    for (int k = 0; k < 64; ++k) s += Wmu[i * 64 + k] * dW1[k * 32 + j];
    C1[idx] = s;
  }
  if (t < 32) {
    float s = db1[t];
    for (int k = 0; k < 64; ++k) s += bmu[k] * dW1[k * 32 + t];
    c1[t] = s;
  }
}

// x (fp32) -> xb (bf16), 8 elems/thread.
__global__ __launch_bounds__(256) void k_cast_x(const float* __restrict__ x,
                                                uint32* __restrict__ xb) {
  int t = blockIdx.x * 256 + threadIdx.x;
  if (t >= NN * 32 / 8) return;
  const float4 f0 = *(const float4*)(x + (long)t * 8);
  const float4 f1 = *(const float4*)(x + (long)t * 8 + 4);
  uint4 o;
  o.x = pack2(f0.x, f0.y);
  o.y = pack2(f0.z, f0.w);
  o.z = pack2(f1.x, f1.y);
  o.w = pack2(f1.z, f1.w);
  *(uint4*)(xb + (long)t * 4) = o;
}

// Segment gather-reduce over bf16 rows, padded CSR (beg = s*CCAP, 16B-aligned).
// 8-wide unrolled: two int4 index loads, 8 outstanding 128B row gathers.
template <int W, bool OUT_F32>
__global__ __launch_bounds__(256) void k_seg_agg(const uint32* __restrict__ tb,
                                                 const int* __restrict__ csr,
                                                 const int* __restrict__ deg,
                                                 const float* __restrict__ inv,
                                                 uint32* __restrict__ dstb,
                                                 float* __restrict__ dstf) {
  constexpr int LANES = W / 8;
  constexpr int ROWU = W / 2;  // uints per row
  int g = blockIdx.x * 256 + threadIdx.x;
  int s = g / LANES;
  int lane = g % LANES;
  if (s >= NE) return;
  int d = deg[s];
  int beg = s * CCAP;
  int end = beg + d;
  float a0 = 0.f, a1 = 0.f, a2 = 0.f, a3 = 0.f;
  float a4 = 0.f, a5 = 0.f, a6 = 0.f, a7 = 0.f;
  const uint32* base = tb + (long)lane * 4;
#define ACC(q)                                        \
  a0 += b2f_lo(q.x); a1 += b2f_hi(q.x);               \
  a2 += b2f_lo(q.y); a3 += b2f_hi(q.y);               \
  a4 += b2f_lo(q.z); a5 += b2f_hi(q.z);               \
  a6 += b2f_lo(q.w); a7 += b2f_hi(q.w);
  int p = beg;
  for (; p + 8 <= end; p += 8) {
    int4 i4a = *(const int4*)(csr + p);
    int4 i4b = *(const int4*)(csr + p + 4);
    uint4 q0 = *(const uint4*)(base + (long)i4a.x * ROWU);
    uint4 q1 = *(const uint4*)(base + (long)i4a.y * ROWU);
    uint4 q2 = *(const uint4*)(base + (long)i4a.z * ROWU);
    uint4 q3 = *(const uint4*)(base + (long)i4a.w * ROWU);
    uint4 q4 = *(const uint4*)(base + (long)i4b.x * ROWU);
    uint4 q5 = *(const uint4*)(base + (long)i4b.y * ROWU);
    uint4 q6 = *(const uint4*)(base + (long)i4b.z * ROWU);
    uint4 q7 = *(const uint4*)(base + (long)i4b.w * ROWU);
    ACC(q0) ACC(q1) ACC(q2) ACC(q3) ACC(q4) ACC(q5) ACC(q6) ACC(q7)
  }
  for (; p + 4 <= end; p += 4) {
    int4 i4 = *(const int4*)(csr + p);
    uint4 q0 = *(const uint4*)(base + (long)i4.x * ROWU);
    uint4 q1 = *(const uint4*)(base + (long)i4.y * ROWU);
    uint4 q2 = *(const uint4*)(base + (long)i4.z * ROWU);
    uint4 q3 = *(const uint4*)(base + (long)i4.w * ROWU);
    ACC(q0) ACC(q1) ACC(q2) ACC(q3)
  }
  for (; p < end; ++p) {
    int idx = csr[p];
    uint4 q = *(const uint4*)(base + (long)idx * ROWU);
    ACC(q)
  }
#undef ACC
  float sc = inv[s];
  a0 *= sc; a1 *= sc; a2 *= sc; a3 *= sc;
  a4 *= sc; a5 *= sc; a6 *= sc; a7 *= sc;
  if (OUT_F32) {
    float* dd = dstf + (long)s * W + lane * 8;
    float4 o0 = {a0, a1, a2, a3};
    float4 o1 = {a4, a5, a6, a7};
    *(float4*)(dd) = o0;
    *(float4*)(dd + 4) = o1;
  } else {
    uint4 o;
    o.x = pack2(a0, a1);
    o.y = pack2(a2, a3);
    o.z = pack2(a4, a5);
    o.w = pack2(a6, a7);
    *(uint4*)(dstb + (long)s * ROWU + lane * 4) = o;
  }
}

// h[r,:] = leaky(LN(a1[r,:]@W1 + b1; g1,be1))   (fp32 32 -> bf16 64)
__global__ __launch_bounds__(256) void k_gemm_ln(const float* __restrict__ a1,
                                                 const float* __restrict__ W1,
                                                 const float* __restrict__ b1,
                                                 const float* __restrict__ g1,
                                                 const float* __restrict__ be1,
                                                 uint32* __restrict__ h) {
  __shared__ float Ws[32 * 64];
  for (int i = threadIdx.x; i < 32 * 64; i += 256) Ws[i] = W1[i];
  __syncthreads();
  int g = blockIdx.x * 256 + threadIdx.x;
  int r = g >> 4;
  int l = (g & 15) * 4;
  if (r >= NN) return;
  const float4* rowv = (const float4*)(a1 + (long)r * 32);
  float vx = b1[l + 0], vy = b1[l + 1], vz = b1[l + 2], vw = b1[l + 3];
#pragma unroll
  for (int kk = 0; kk < 8; ++kk) {
    float4 rv = rowv[kk];
    const float* w0 = &Ws[(4 * kk + 0) * 64 + l];
    const float* w1 = &Ws[(4 * kk + 1) * 64 + l];
    const float* w2 = &Ws[(4 * kk + 2) * 64 + l];
    const float* w3 = &Ws[(4 * kk + 3) * 64 + l];
    vx += rv.x * w0[0] + rv.y * w1[0] + rv.z * w2[0] + rv.w * w3[0];
    vy += rv.x * w0[1] + rv.y * w1[1] + rv.z * w2[1] + rv.w * w3[1];
    vz += rv.x * w0[2] + rv.y * w1[2] + rv.z * w2[2] + rv.w * w3[2];
    vw += rv.x * w0[3] + rv.y * w1[3] + rv.z * w2[3] + rv.w * w3[3];
  }
  float s = vx + vy + vz + vw;
  float s2 = vx * vx + vy * vy + vz * vz + vw * vw;
  for (int m = 1; m <= 8; m <<= 1) {
    s += __shfl_xor(s, m, 64);
    s2 += __shfl_xor(s2, m, 64);
  }
  float mean = s * (1.0f / 64.0f);
  float var = s2 * (1.0f / 64.0f) - mean * mean;
  float rstd = rsqrtf(var + 1e-5f);
  float ox = (vx - mean) * rstd * g1[l + 0] + be1[l + 0];
  float oy = (vy - mean) * rstd * g1[l + 1] + be1[l + 1];
  float oz = (vz - mean) * rstd * g1[l + 2] + be1[l + 2];
  float ow = (vw - mean) * rstd * g1[l + 3] + be1[l + 3];
  ox = ox >= 0.f ? ox : 0.01f * ox;
  oy = oy >= 0.f ? oy : 0.01f * oy;
  oz = oz >= 0.f ? oz : 0.01f * oz;
  ow = ow >= 0.f ? ow : 0.01f * ow;
  uint2 o = {pack2(ox, oy), pack2(oz, ow)};
  *(uint2*)(h + (long)r * 32 + (l >> 1)) = o;
}

// h2[r,:] = leaky(a2[r,:]@W2 + b2)   (fp32 64 -> bf16 64)
__global__ __launch_bounds__(256) void k_gemm_leaky(const float* __restrict__ a2,
                                                    const float* __restrict__ W2,
                                                    const float* __restrict__ b2,
                                                    uint32* __restrict__ h2) {
  __shared__ float Ws[64 * 64];
  for (int i = threadIdx.x; i < 64 * 64; i += 256) Ws[i] = W2[i];
  __syncthreads();
  int g = blockIdx.x * 256 + threadIdx.x;
  int r = g >> 4;
  int l = (g & 15) * 4;
  if (r >= NN) return;
  const float4* rowv = (const float4*)(a2 + (long)r * 64);
  float vx = b2[l + 0], vy = b2[l + 1], vz = b2[l + 2], vw = b2[l + 3];
#pragma unroll
  for (int kk = 0; kk < 16; ++kk) {
    float4 rv = rowv[kk];
    const float* w0 = &Ws[(4 * kk + 0) * 64 + l];
    const float* w1 = &Ws[(4 * kk + 1) * 64 + l];
    const float* w2 = &Ws[(4 * kk + 2) * 64 + l];
    const float* w3 = &Ws[(4 * kk + 3) * 64 + l];
    vx += rv.x * w0[0] + rv.y * w1[0] + rv.z * w2[0] + rv.w * w3[0];
    vy += rv.x * w0[1] + rv.y * w1[1] + rv.z * w2[1] + rv.w * w3[1];
    vz += rv.x * w0[2] + rv.y * w1[2] + rv.z * w2[2] + rv.w * w3[2];
    vw += rv.x * w0[3] + rv.y * w1[3] + rv.z * w2[3] + rv.w * w3[3];
  }
  vx = vx >= 0.f ? vx : 0.01f * vx;
  vy = vy >= 0.f ? vy : 0.01f * vy;
  vz = vz >= 0.f ? vz : 0.01f * vz;
  vw = vw >= 0.f ? vw : 0.01f * vw;
  uint2 o = {pack2(vx, vy), pack2(vz, vw)};
  *(uint2*)(h2 + (long)r * 32 + (l >> 1)) = o;
}

// Fused logvar GEMM + composed decode + norm accumulate. One pass over a3.
// 16 lanes per row: lv outputs 4/lane; decode hidden units 2/lane, partial
// a2[8] shfl-reduced across the 16-lane group; lane 0 finishes 8->1.
__global__ __launch_bounds__(256) void k_lv_dec(
    const float* __restrict__ a3, const float* __restrict__ Wlv,
    const float* __restrict__ blv, const float* __restrict__ C1,
    const float* __restrict__ c1, const float* __restrict__ dW2,
    const float* __restrict__ db2, const float* __restrict__ dW3,
    const float* __restrict__ db3, float* __restrict__ out,
    float* __restrict__ lv, float* __restrict__ norm_acc) {
  __shared__ float Ws[64 * 64];
  __shared__ float C1s[64 * 32];
  __shared__ float W2s[32 * 8];
  __shared__ float W3s[8];
  __shared__ float c1s[32];
  __shared__ float b2s[8];
  __shared__ float b3s;
  __shared__ float red[16];
  for (int i = threadIdx.x; i < 64 * 64; i += 256) Ws[i] = Wlv[i];
  for (int i = threadIdx.x; i < 64 * 32; i += 256) C1s[i] = C1[i];
  if (threadIdx.x < 256) W2s[threadIdx.x] = dW2[threadIdx.x];
  if (threadIdx.x < 32) c1s[threadIdx.x] = c1[threadIdx.x];
  if (threadIdx.x < 8) {
    W3s[threadIdx.x] = dW3[threadIdx.x];
    b2s[threadIdx.x] = db2[threadIdx.x];
  }
  if (threadIdx.x == 0) b3s = db3[0];
  __syncthreads();
  int g = blockIdx.x * 256 + threadIdx.x;
  int r = g >> 4;
  int sub = g & 15;
  int l = sub * 4;
  int j0 = 2 * sub, j1 = 2 * sub + 1;
  const float4* rowv = (const float4*)(a3 + (long)r * 64);
  float vx = blv[l + 0], vy = blv[l + 1], vz = blv[l + 2], vw = blv[l + 3];
  float accj0 = c1s[j0], accj1 = c1s[j1];
#pragma unroll
  for (int kk = 0; kk < 16; ++kk) {
    float4 rv = rowv[kk];
    const float* w0 = &Ws[(4 * kk + 0) * 64 + l];
    const float* w1 = &Ws[(4 * kk + 1) * 64 + l];
    const float* w2 = &Ws[(4 * kk + 2) * 64 + l];
    const float* w3 = &Ws[(4 * kk + 3) * 64 + l];
    vx += rv.x * w0[0] + rv.y * w1[0] + rv.z * w2[0] + rv.w * w3[0];
    vy += rv.x * w0[1] + rv.y * w1[1] + rv.z * w2[1] + rv.w * w3[1];
    vz += rv.x * w0[2] + rv.y * w1[2] + rv.z * w2[2] + rv.w * w3[2];
    vw += rv.x * w0[3] + rv.y * w1[3] + rv.z * w2[3] + rv.w * w3[3];
    const float* c0 = &C1s[(4 * kk + 0) * 32];
    const float* c1p = &C1s[(4 * kk + 1) * 32];
    const float* c2 = &C1s[(4 * kk + 2) * 32];
    const float* c3 = &C1s[(4 * kk + 3) * 32];
    accj0 += rv.x * c0[j0] + rv.y * c1p[j0] + rv.z * c2[j0] + rv.w * c3[j0];
    accj1 += rv.x * c0[j1] + rv.y * c1p[j1] + rv.z * c2[j1] + rv.w * c3[j1];
  }
  // lv write
  float4 olv = {vx, vy, vz, vw};
  *(float4*)(&lv[(long)r * 64 + l]) = olv;
  // decode: leaky on hidden, partial a2
  float v0 = accj0 >= 0.f ? accj0 : 0.01f * accj0;
  float v1 = accj1 >= 0.f ? accj1 : 0.01f * accj1;
  float a2p[8];
#pragma unroll
  for (int m = 0; m < 8; ++m)
    a2p[m] = v0 * W2s[j0 * 8 + m] + v1 * W2s[j1 * 8 + m];
#pragma unroll
  for (int mask = 1; mask <= 8; mask <<= 1) {
#pragma unroll
    for (int m = 0; m < 8; ++m) a2p[m] += __shfl_xor(a2p[m], mask, 64);
  }
  float dval = 0.f;
  if (sub == 0) {
    float s = b3s;
#pragma unroll
    for (int k = 0; k < 8; ++k) {
      float v = a2p[k] + b2s[k];
      v = v >= 0.f ? v : 0.01f * v;
      s += v * W3s[k];
    }
    dval = s;
    out[r] = dval;        // z_orth (unscaled)
    out[NN + r] = dval;   // mu_orth (z == mu in eval mode)
    red[threadIdx.x >> 4] = dval * dval;
  }
  __syncthreads();
  if (threadIdx.x == 0) {
    float t = 0.f;
#pragma unroll
    for (int k = 0; k < 16; ++k) t += red[k];
    atomicAdd(norm_acc, t);
  }
}

__global__ __launch_bounds__(256) void k_scale(float* __restrict__ out,
                                               const float* __restrict__ norm_acc) {
  int i = blockIdx.x * 256 + threadIdx.x;
  if (i < 2 * NN) {
    float nrm = sqrtf(*norm_acc);
    float sc = 1.0f / fmaxf(nrm, 1e-8f);
    out[i] *= sc;
  }
}

extern "C" void kernel_launch(void* const* d_in, const int* in_sizes, int n_in,
                              void* d_out, int out_size, void* d_ws, size_t ws_size,
                              hipStream_t stream) {
  const float* x   = (const float*)d_in[0];
  const int*   hei = (const int*)d_in[1];  // [2, NP]
  const int* nidx = hei;
  const int* eidx = hei + NP;
  const float* W1  = (const float*)d_in[2];
  const float* b1  = (const float*)d_in[3];
  const float* g1  = (const float*)d_in[4];
  const float* be1 = (const float*)d_in[5];
  const float* W2  = (const float*)d_in[6];
  const float* b2  = (const float*)d_in[7];
  const float* Wmu = (const float*)d_in[8];
  const float* bmu = (const float*)d_in[9];
  const float* Wlv = (const float*)d_in[10];
  const float* blv = (const float*)d_in[11];
  const float* dW1 = (const float*)d_in[12];
  const float* db1 = (const float*)d_in[13];
  const float* dW2 = (const float*)d_in[14];
  const float* db2 = (const float*)d_in[15];
  const float* dW3 = (const float*)d_in[16];
  const float* db3 = (const float*)d_in[17];
  float* out = (float*)d_out;

  int*    wi = (int*)d_ws;
  float*  wf = (float*)d_ws;
  uint32* wu = (uint32*)d_ws;

  // zero gcurE/gcurN/norm (words 0 .. 1087)
  hipMemsetAsync(d_ws, 0, (size_t)1088 * 4, stream);

  // CSR build: bucketize, then per-bucket LDS counting sort (both sides)
  k_bucket<<<(NP + 4095) / 4096, 256, 0, stream>>>(nidx, eidx,
                                                   wi + O_GCURE, wi + O_GCURN,
                                                   wi + O_BKTE, wi + O_BKTN);
  k_csr2<<<2 * NBK, 256, 0, stream>>>(wi + O_GCURE, wi + O_GCURN,
                                      wi + O_BKTE, wi + O_BKTN,
                                      wi + O_CSRE, wi + O_CSRN,
                                      wi + O_DEGE, wi + O_DEGN,
                                      wf + O_BINV, wf + O_DINV);

  k_compose<<<1, 256, 0, stream>>>(Wmu, bmu, dW1, db1, wf + O_C1, wf + O_C1B);
  k_cast_x<<<(NN * 32 / 8 + 255) / 256, 256, 0, stream>>>(x, wu + O_XB);

  const int G32 = (NE * 4 + 255) / 256;   // 4 lanes/row, bf16 32-wide
  const int G64 = (NE * 8 + 255) / 256;   // 8 lanes/row, bf16 64-wide
  const int GG  = NN * 16 / 256;          // row kernels, 16 lanes/row

  // layer 1 (aggregate bf16 32-wide, then GEMM+LN+leaky -> bf16 t)
  k_seg_agg<32, false><<<G32, 256, 0, stream>>>(wu + O_XB, wi + O_CSRE,
                                                wi + O_DEGE, wf + O_BINV,
                                                wu + O_HE, nullptr);
  k_seg_agg<32, true><<<G32, 256, 0, stream>>>(wu + O_HE, wi + O_CSRN,
                                               wi + O_DEGN, wf + O_DINV,
                                               nullptr, wf + O_A);
  k_gemm_ln<<<GG, 256, 0, stream>>>(wf + O_A, W1, b1, g1, be1, wu + O_T);

  // layer 2
  k_seg_agg<64, false><<<G64, 256, 0, stream>>>(wu + O_T, wi + O_CSRE,
                                                wi + O_DEGE, wf + O_BINV,
                                                wu + O_HE, nullptr);
  k_seg_agg<64, true><<<G64, 256, 0, stream>>>(wu + O_HE, wi + O_CSRN,
                                               wi + O_DEGN, wf + O_DINV,
                                               nullptr, wf + O_A);
  k_gemm_leaky<<<GG, 256, 0, stream>>>(wf + O_A, W2, b2, wu + O_T);

  // heads: one shared aggregation; fused logvar GEMM + composed decode
  k_seg_agg<64, false><<<G64, 256, 0, stream>>>(wu + O_T, wi + O_CSRE,
                                                wi + O_DEGE, wf + O_BINV,
                                                wu + O_HE, nullptr);
  k_seg_agg<64, true><<<G64, 256, 0, stream>>>(wu + O_HE, wi + O_CSRN,
                                               wi + O_DEGN, wf + O_DINV,
                                               nullptr, wf + O_A);
  k_lv_dec<<<GG, 256, 0, stream>>>(wf + O_A, Wlv, blv, wf + O_C1, wf + O_C1B,
                                   dW2, db2, dW3, db3,
                                   out, out + 2 * NN, wf + O_NORM);
  k_scale<<<(2 * NN + 255) / 256, 256, 0, stream>>>(out, wf + O_NORM);
}

// Round 10
// 433.097 us; speedup vs baseline: 1.1208x; 1.1208x over previous
//
#include <hip/hip_runtime.h>

// HypergraphModel on MI355X.
// R10: revert R9's k_lv_dec fusion (95 us, 1.2M LDS bank conflicts from the
//      32x shfl_xor a2-reduction — cross-lane reduce swamped the saved pass).
//      Restore R8's split k_gemm_lv + k_decode (one thread per row, no
//      shuffles). KEEP R9's wins: k_bucket @ 4096 pins/block, 8-wide
//      unrolled seg_agg gathers. CSR counting sort + composed mu unchanged.

#define NN 100000
#define NE 100000
#define NP 1600000
#define NBK  391   // buckets per side (256 ids each); NBK*256 = 100,096
#define BCAP 4608  // bucket cap (mean 4096, +8 sigma)
#define CCAP 48    // padded CSR row stride (Poisson(16) + >8 sigma)

// ws offsets in 4-byte words (sizes in words) — non-overlapping:
#define O_GCURE 0              // 512  (zeroed)
#define O_GCURN 512            // 512  (zeroed)
#define O_NORM  1024           // 64   (zeroed)
#define O_DEGE  1088           // 100,000
#define O_DEGN  101088         // 100,000
#define O_BINV  201088         // 100,000
#define O_DINV  301088         // 100,000
#define O_BKTE  401088         // NBK*BCAP = 1,801,728
#define O_BKTN  2202816        // 1,801,728
#define O_CSRE  4004544        // NE*CCAP = 4,800,000
#define O_CSRN  8804544        // 4,800,000
#define O_XB    13604544       // bf16 100000x32 = 1,600,000 words
#define O_T     15204544       // bf16 100000x64 = 3,200,000 words
#define O_HE    18404544       // bf16 100000x64 = 3,200,000 words
#define O_A     21604544       // fp32 100000x64 = 6,400,000 words
#define O_C1    28004544       // fp32 64x32 = 2,048 (composed Wmu@dW1)
#define O_C1B   28006592       // fp32 32 (composed bias)
// end 28,006,624 words = 112 MB

typedef unsigned int uint32;

__device__ __forceinline__ float b2f_lo(uint32 u) { return __uint_as_float(u << 16); }
__device__ __forceinline__ float b2f_hi(uint32 u) { return __uint_as_float(u & 0xFFFF0000u); }
__device__ __forceinline__ uint32 f2b(float f) {  // RNE fp32 -> bf16
  uint32 b = __float_as_uint(f);
  return (b + 0x7FFFu + ((b >> 16) & 1u)) >> 16;
}
__device__ __forceinline__ uint32 pack2(float lo, float hi) {
  return f2b(lo) | (f2b(hi) << 16);
}

// ---- Pass A: bucketize pins (4096 pins/block, 16/thread).
__global__ __launch_bounds__(256) void k_bucket(const int* __restrict__ nidx,
                                                const int* __restrict__ eidx,
                                                int* __restrict__ gcurE,
                                                int* __restrict__ gcurN,
                                                int* __restrict__ bktE,
                                                int* __restrict__ bktN) {
  __shared__ int cntE[NBK], cntN[NBK], curE[NBK], curN[NBK];
  for (int i = threadIdx.x; i < NBK; i += 256) { cntE[i] = 0; cntN[i] = 0; }
  __syncthreads();
  int base = blockIdx.x * 4096 + threadIdx.x * 16;
  int n[16], e[16];
  int cnt = 0;
  if (base + 16 <= NP) {
#pragma unroll
    for (int q = 0; q < 4; ++q) {
      int4 a = *(const int4*)(nidx + base + 4 * q);
      int4 b = *(const int4*)(eidx + base + 4 * q);
      n[4 * q + 0] = a.x; n[4 * q + 1] = a.y; n[4 * q + 2] = a.z; n[4 * q + 3] = a.w;
      e[4 * q + 0] = b.x; e[4 * q + 1] = b.y; e[4 * q + 2] = b.z; e[4 * q + 3] = b.w;
    }
    cnt = 16;
  } else {
    for (int i = 0; i < 16 && base + i < NP; ++i) {
      n[i] = nidx[base + i];
      e[i] = eidx[base + i];
      ++cnt;
    }
  }
  for (int i = 0; i < cnt; ++i) {
    atomicAdd(&cntE[e[i] >> 8], 1);
    atomicAdd(&cntN[n[i] >> 8], 1);
  }
  __syncthreads();
  for (int i = threadIdx.x; i < NBK; i += 256) {
    curE[i] = atomicAdd(&gcurE[i], cntE[i]);
    curN[i] = atomicAdd(&gcurN[i], cntN[i]);
  }
  __syncthreads();
  for (int i = 0; i < cnt; ++i) {
    int be = e[i] >> 8, bn = n[i] >> 8;
    int se = atomicAdd(&curE[be], 1);
    if (se < BCAP) bktE[be * BCAP + se] = ((e[i] & 255) << 24) | n[i];
    int sn = atomicAdd(&curN[bn], 1);
    if (sn < BCAP) bktN[bn * BCAP + sn] = ((n[i] & 255) << 24) | e[i];
  }
}

// ---- Pass B: per-bucket padded-CSR build + deg + 1/deg (LDS atomics only).
__global__ __launch_bounds__(256) void k_csr2(const int* __restrict__ gcurE,
                                              const int* __restrict__ gcurN,
                                              const int* __restrict__ bktE,
                                              const int* __restrict__ bktN,
                                              int* __restrict__ csrE,
                                              int* __restrict__ csrN,
                                              int* __restrict__ degE,
                                              int* __restrict__ degN,
                                              float* __restrict__ invE,
                                              float* __restrict__ invN) {
  int bb = blockIdx.x;
  bool es = bb < NBK;
  int b = es ? bb : bb - NBK;
  const int* gcur = es ? gcurE : gcurN;
  const int* bkt  = es ? bktE : bktN;
  int*   csr = es ? csrE : csrN;
  int*   deg = es ? degE : degN;
  float* inv = es ? invE : invN;

  __shared__ int ent[BCAP];
  __shared__ int cnt[256], cur[256];
  int m = gcur[b];
  if (m > BCAP) m = BCAP;
  for (int i = threadIdx.x; i < m; i += 256) ent[i] = bkt[b * BCAP + i];
  cnt[threadIdx.x] = 0;
  __syncthreads();
  for (int i = threadIdx.x; i < m; i += 256)
    atomicAdd(&cnt[((unsigned)ent[i]) >> 24], 1);
  __syncthreads();
  int id = (b << 8) + threadIdx.x;
  if (id < NN) {  // NN == NE
    int d = cnt[threadIdx.x];
    deg[id] = d < CCAP ? d : CCAP;
    inv[id] = d > 0 ? 1.0f / (float)d : 0.0f;
  }
  cur[threadIdx.x] = 0;
  __syncthreads();
  for (int i = threadIdx.x; i < m; i += 256) {
    unsigned v = (unsigned)ent[i];
    int loc = v >> 24;
    int payload = v & 0xFFFFFF;
    int slot = atomicAdd(&cur[loc], 1);
    if (slot < CCAP) csr[(long)((b << 8) + loc) * CCAP + slot] = payload;
  }
}

// Compose decode layer1 with the mu head: C1 = Wmu@dW1, c1 = bmu@dW1 + db1.
__global__ __launch_bounds__(256) void k_compose(const float* __restrict__ Wmu,
                                                 const float* __restrict__ bmu,
                                                 const float* __restrict__ dW1,
                                                 const float* __restrict__ db1,
                                                 float* __restrict__ C1,
                                                 float* __restrict__ c1) {
  int t = threadIdx.x;
  for (int idx = t; idx < 64 * 32; idx += 256) {
    int i = idx >> 5, j = idx & 31;
    float s = 0.f;
    for (int k = 0; k < 64; ++k) s += Wmu[i * 64 + k] * dW1[k * 32 + j];
    C1[idx] = s;
  }
  if (t < 32) {
    float s = db1[t];
    for (int k = 0; k < 64; ++k) s += bmu[k] * dW1[k * 32 + t];
    c1[t] = s;
  }
}

// x (fp32) -> xb (bf16), 8 elems/thread.
__global__ __launch_bounds__(256) void k_cast_x(const float* __restrict__ x,
                                                uint32* __restrict__ xb) {
  int t = blockIdx.x * 256 + threadIdx.x;
  if (t >= NN * 32 / 8) return;
  const float4 f0 = *(const float4*)(x + (long)t * 8);
  const float4 f1 = *(const float4*)(x + (long)t * 8 + 4);
  uint4 o;
  o.x = pack2(f0.x, f0.y);
  o.y = pack2(f0.z, f0.w);
  o.z = pack2(f1.x, f1.y);
  o.w = pack2(f1.z, f1.w);
  *(uint4*)(xb + (long)t * 4) = o;
}

// Segment gather-reduce over bf16 rows, padded CSR (beg = s*CCAP, 16B-aligned).
// 8-wide unrolled: two int4 index loads, 8 outstanding row gathers.
template <int W, bool OUT_F32>
__global__ __launch_bounds__(256) void k_seg_agg(const uint32* __restrict__ tb,
                                                 const int* __restrict__ csr,
                                                 const int* __restrict__ deg,
                                                 const float* __restrict__ inv,
                                                 uint32* __restrict__ dstb,
                                                 float* __restrict__ dstf) {
  constexpr int LANES = W / 8;
  constexpr int ROWU = W / 2;  // uints per row
  int g = blockIdx.x * 256 + threadIdx.x;
  int s = g / LANES;
  int lane = g % LANES;
  if (s >= NE) return;
  int d = deg[s];
  int beg = s * CCAP;
  int end = beg + d;
  float a0 = 0.f, a1 = 0.f, a2 = 0.f, a3 = 0.f;
  float a4 = 0.f, a5 = 0.f, a6 = 0.f, a7 = 0.f;
  const uint32* base = tb + (long)lane * 4;
#define ACC(q)                                        \
  a0 += b2f_lo(q.x); a1 += b2f_hi(q.x);               \
  a2 += b2f_lo(q.y); a3 += b2f_hi(q.y);               \
  a4 += b2f_lo(q.z); a5 += b2f_hi(q.z);               \
  a6 += b2f_lo(q.w); a7 += b2f_hi(q.w);
  int p = beg;
  for (; p + 8 <= end; p += 8) {
    int4 i4a = *(const int4*)(csr + p);
    int4 i4b = *(const int4*)(csr + p + 4);
    uint4 q0 = *(const uint4*)(base + (long)i4a.x * ROWU);
    uint4 q1 = *(const uint4*)(base + (long)i4a.y * ROWU);
    uint4 q2 = *(const uint4*)(base + (long)i4a.z * ROWU);
    uint4 q3 = *(const uint4*)(base + (long)i4a.w * ROWU);
    uint4 q4 = *(const uint4*)(base + (long)i4b.x * ROWU);
    uint4 q5 = *(const uint4*)(base + (long)i4b.y * ROWU);
    uint4 q6 = *(const uint4*)(base + (long)i4b.z * ROWU);
    uint4 q7 = *(const uint4*)(base + (long)i4b.w * ROWU);
    ACC(q0) ACC(q1) ACC(q2) ACC(q3) ACC(q4) ACC(q5) ACC(q6) ACC(q7)
  }
  for (; p + 4 <= end; p += 4) {
    int4 i4 = *(const int4*)(csr + p);
    uint4 q0 = *(const uint4*)(base + (long)i4.x * ROWU);
    uint4 q1 = *(const uint4*)(base + (long)i4.y * ROWU);
    uint4 q2 = *(const uint4*)(base + (long)i4.z * ROWU);
    uint4 q3 = *(const uint4*)(base + (long)i4.w * ROWU);
    ACC(q0) ACC(q1) ACC(q2) ACC(q3)
  }
  for (; p < end; ++p) {
    int idx = csr[p];
    uint4 q = *(const uint4*)(base + (long)idx * ROWU);
    ACC(q)
  }
#undef ACC
  float sc = inv[s];
  a0 *= sc; a1 *= sc; a2 *= sc; a3 *= sc;
  a4 *= sc; a5 *= sc; a6 *= sc; a7 *= sc;
  if (OUT_F32) {
    float* dd = dstf + (long)s * W + lane * 8;
    float4 o0 = {a0, a1, a2, a3};
    float4 o1 = {a4, a5, a6, a7};
    *(float4*)(dd) = o0;
    *(float4*)(dd + 4) = o1;
  } else {
    uint4 o;
    o.x = pack2(a0, a1);
    o.y = pack2(a2, a3);
    o.z = pack2(a4, a5);
    o.w = pack2(a6, a7);
    *(uint4*)(dstb + (long)s * ROWU + lane * 4) = o;
  }
}

// h[r,:] = leaky(LN(a1[r,:]@W1 + b1; g1,be1))   (fp32 32 -> bf16 64)
__global__ __launch_bounds__(256) void k_gemm_ln(const float* __restrict__ a1,
                                                 const float* __restrict__ W1,
                                                 const float* __restrict__ b1,
                                                 const float* __restrict__ g1,
                                                 const float* __restrict__ be1,
                                                 uint32* __restrict__ h) {
  __shared__ float Ws[32 * 64];
  for (int i = threadIdx.x; i < 32 * 64; i += 256) Ws[i] = W1[i];
  __syncthreads();
  int g = blockIdx.x * 256 + threadIdx.x;
  int r = g >> 4;
  int l = (g & 15) * 4;
  if (r >= NN) return;
  const float4* rowv = (const float4*)(a1 + (long)r * 32);
  float vx = b1[l + 0], vy = b1[l + 1], vz = b1[l + 2], vw = b1[l + 3];
#pragma unroll
  for (int kk = 0; kk < 8; ++kk) {
    float4 rv = rowv[kk];
    const float* w0 = &Ws[(4 * kk + 0) * 64 + l];
    const float* w1 = &Ws[(4 * kk + 1) * 64 + l];
    const float* w2 = &Ws[(4 * kk + 2) * 64 + l];
    const float* w3 = &Ws[(4 * kk + 3) * 64 + l];
    vx += rv.x * w0[0] + rv.y * w1[0] + rv.z * w2[0] + rv.w * w3[0];
    vy += rv.x * w0[1] + rv.y * w1[1] + rv.z * w2[1] + rv.w * w3[1];
    vz += rv.x * w0[2] + rv.y * w1[2] + rv.z * w2[2] + rv.w * w3[2];
    vw += rv.x * w0[3] + rv.y * w1[3] + rv.z * w2[3] + rv.w * w3[3];
  }
  float s = vx + vy + vz + vw;
  float s2 = vx * vx + vy * vy + vz * vz + vw * vw;
  for (int m = 1; m <= 8; m <<= 1) {
    s += __shfl_xor(s, m, 64);
    s2 += __shfl_xor(s2, m, 64);
  }
  float mean = s * (1.0f / 64.0f);
  float var = s2 * (1.0f / 64.0f) - mean * mean;
  float rstd = rsqrtf(var + 1e-5f);
  float ox = (vx - mean) * rstd * g1[l + 0] + be1[l + 0];
  float oy = (vy - mean) * rstd * g1[l + 1] + be1[l + 1];
  float oz = (vz - mean) * rstd * g1[l + 2] + be1[l + 2];
  float ow = (vw - mean) * rstd * g1[l + 3] + be1[l + 3];
  ox = ox >= 0.f ? ox : 0.01f * ox;
  oy = oy >= 0.f ? oy : 0.01f * oy;
  oz = oz >= 0.f ? oz : 0.01f * oz;
  ow = ow >= 0.f ? ow : 0.01f * ow;
  uint2 o = {pack2(ox, oy), pack2(oz, ow)};
  *(uint2*)(h + (long)r * 32 + (l >> 1)) = o;
}

// h2[r,:] = leaky(a2[r,:]@W2 + b2)   (fp32 64 -> bf16 64)
__global__ __launch_bounds__(256) void k_gemm_leaky(const float* __restrict__ a2,
                                                    const float* __restrict__ W2,
                                                    const float* __restrict__ b2,
                                                    uint32* __restrict__ h2) {
  __shared__ float Ws[64 * 64];
  for (int i = threadIdx.x; i < 64 * 64; i += 256) Ws[i] = W2[i];
  __syncthreads();
  int g = blockIdx.x * 256 + threadIdx.x;
  int r = g >> 4;
  int l = (g & 15) * 4;
  if (r >= NN) return;
  const float4* rowv = (const float4*)(a2 + (long)r * 64);
  float vx = b2[l + 0], vy = b2[l + 1], vz = b2[l + 2], vw = b2[l + 3];
#pragma unroll
  for (int kk = 0; kk < 16; ++kk) {
    float4 rv = rowv[kk];
    const float* w0 = &Ws[(4 * kk + 0) * 64 + l];
    const float* w1 = &Ws[(4 * kk + 1) * 64 + l];
    const float* w2 = &Ws[(4 * kk + 2) * 64 + l];
    const float* w3 = &Ws[(4 * kk + 3) * 64 + l];
    vx += rv.x * w0[0] + rv.y * w1[0] + rv.z * w2[0] + rv.w * w3[0];
    vy += rv.x * w0[1] + rv.y * w1[1] + rv.z * w2[1] + rv.w * w3[1];
    vz += rv.x * w0[2] + rv.y * w1[2] + rv.z * w2[2] + rv.w * w3[2];
    vw += rv.x * w0[3] + rv.y * w1[3] + rv.z * w2[3] + rv.w * w3[3];
  }
  vx = vx >= 0.f ? vx : 0.01f * vx;
  vy = vy >= 0.f ? vy : 0.01f * vy;
  vz = vz >= 0.f ? vz : 0.01f * vz;
  vw = vw >= 0.f ? vw : 0.01f * vw;
  uint2 o = {pack2(vx, vy), pack2(vz, vw)};
  *(uint2*)(h2 + (long)r * 32 + (l >> 1)) = o;
}

// logvar head only: lv[r,:] = a3@Wlv + blv   (fp32 in/out, 16 KB LDS)
__global__ __launch_bounds__(256) void k_gemm_lv(const float* __restrict__ a3,
                                                 const float* __restrict__ Wlv,
                                                 const float* __restrict__ blv,
                                                 float* __restrict__ lv) {
  __shared__ float Ws[64 * 64];
  for (int i = threadIdx.x; i < 64 * 64; i += 256) Ws[i] = Wlv[i];
  __syncthreads();
  int g = blockIdx.x * 256 + threadIdx.x;
  int r = g >> 4;
  int l = (g & 15) * 4;
  if (r >= NN) return;
  const float4* rowv = (const float4*)(a3 + (long)r * 64);
  float vx = blv[l + 0], vy = blv[l + 1], vz = blv[l + 2], vw = blv[l + 3];
#pragma unroll
  for (int kk = 0; kk < 16; ++kk) {
    float4 rv = rowv[kk];
    const float* w0 = &Ws[(4 * kk + 0) * 64 + l];
    const float* w1 = &Ws[(4 * kk + 1) * 64 + l];
    const float* w2 = &Ws[(4 * kk + 2) * 64 + l];
    const float* w3 = &Ws[(4 * kk + 3) * 64 + l];
    vx += rv.x * w0[0] + rv.y * w1[0] + rv.z * w2[0] + rv.w * w3[0];
    vy += rv.x * w0[1] + rv.y * w1[1] + rv.z * w2[1] + rv.w * w3[1];
    vz += rv.x * w0[2] + rv.y * w1[2] + rv.z * w2[2] + rv.w * w3[2];
    vw += rv.x * w0[3] + rv.y * w1[3] + rv.z * w2[3] + rv.w * w3[3];
  }
  float4 o = {vx, vy, vz, vw};
  *(float4*)(&lv[(long)r * 64 + l]) = o;
}

// decode directly from a3 via composed C1/c1 (mu never materialized), then
// 32->8->1 with leaky; writes z_orth & mu_orth (identical) + norm accumulate.
__global__ __launch_bounds__(256) void k_decode(
    const float* __restrict__ a3, const float* __restrict__ C1,
    const float* __restrict__ c1, const float* __restrict__ dW2,
    const float* __restrict__ db2, const float* __restrict__ dW3,
    const float* __restrict__ db3, float* __restrict__ out,
    float* __restrict__ norm_acc) {
  __shared__ float C1s[64 * 32];
  __shared__ float W2s[32 * 8];
  __shared__ float W3s[8];
  __shared__ float c1s[32];
  __shared__ float b2s[8];
  __shared__ float b3s;
  for (int i = threadIdx.x; i < 2048; i += 256) C1s[i] = C1[i];
  if (threadIdx.x < 256) W2s[threadIdx.x] = dW2[threadIdx.x];
  if (threadIdx.x < 32) c1s[threadIdx.x] = c1[threadIdx.x];
  if (threadIdx.x < 8) {
    W3s[threadIdx.x] = dW3[threadIdx.x];
    b2s[threadIdx.x] = db2[threadIdx.x];
  }
  if (threadIdx.x == 0) b3s = db3[0];
  __syncthreads();
  int n = blockIdx.x * 256 + threadIdx.x;
  float dval = 0.0f;
  if (n < NN) {
    float acc[32];
#pragma unroll
    for (int j = 0; j < 32; ++j) acc[j] = c1s[j];
    const float4* rowv = (const float4*)(a3 + (long)n * 64);
    for (int kk = 0; kk < 16; ++kk) {
      float4 rv = rowv[kk];
      const float* r0 = &C1s[(4 * kk + 0) * 32];
      const float* r1 = &C1s[(4 * kk + 1) * 32];
      const float* r2 = &C1s[(4 * kk + 2) * 32];
      const float* r3 = &C1s[(4 * kk + 3) * 32];
#pragma unroll
      for (int j = 0; j < 32; ++j)
        acc[j] += rv.x * r0[j] + rv.y * r1[j] + rv.z * r2[j] + rv.w * r3[j];
    }
    float a2[8];
#pragma unroll
    for (int j = 0; j < 8; ++j) a2[j] = b2s[j];
#pragma unroll
    for (int k = 0; k < 32; ++k) {
      float v = acc[k];
      v = v >= 0.f ? v : 0.01f * v;
#pragma unroll
      for (int j = 0; j < 8; ++j) a2[j] += v * W2s[k * 8 + j];
    }
    float s = b3s;
#pragma unroll
    for (int k = 0; k < 8; ++k) {
      float v = a2[k];
      v = v >= 0.f ? v : 0.01f * v;
      s += v * W3s[k];
    }
    dval = s;
    out[n] = dval;        // z_orth (unscaled)
    out[NN + n] = dval;   // mu_orth (z == mu in eval mode)
  }
  __shared__ float red[256];
  red[threadIdx.x] = dval * dval;
  __syncthreads();
  for (int off = 128; off > 0; off >>= 1) {
    if (threadIdx.x < off) red[threadIdx.x] += red[threadIdx.x + off];
    __syncthreads();
  }
  if (threadIdx.x == 0) atomicAdd(norm_acc, red[0]);
}

__global__ __launch_bounds__(256) void k_scale(float* __restrict__ out,
                                               const float* __restrict__ norm_acc) {
  int i = blockIdx.x * 256 + threadIdx.x;
  if (i < 2 * NN) {
    float nrm = sqrtf(*norm_acc);
    float sc = 1.0f / fmaxf(nrm, 1e-8f);
    out[i] *= sc;
  }
}

extern "C" void kernel_launch(void* const* d_in, const int* in_sizes, int n_in,
                              void* d_out, int out_size, void* d_ws, size_t ws_size,
                              hipStream_t stream) {
  const float* x   = (const float*)d_in[0];
  const int*   hei = (const int*)d_in[1];  // [2, NP]
  const int* nidx = hei;
  const int* eidx = hei + NP;
  const float* W1  = (const float*)d_in[2];
  const float* b1  = (const float*)d_in[3];
  const float* g1  = (const float*)d_in[4];
  const float* be1 = (const float*)d_in[5];
  const float* W2  = (const float*)d_in[6];
  const float* b2  = (const float*)d_in[7];
  const float* Wmu = (const float*)d_in[8];
  const float* bmu = (const float*)d_in[9];
  const float* Wlv = (const float*)d_in[10];
  const float* blv = (const float*)d_in[11];
  const float* dW1 = (const float*)d_in[12];
  const float* db1 = (const float*)d_in[13];
  const float* dW2 = (const float*)d_in[14];
  const float* db2 = (const float*)d_in[15];
  const float* dW3 = (const float*)d_in[16];
  const float* db3 = (const float*)d_in[17];
  float* out = (float*)d_out;

  int*    wi = (int*)d_ws;
  float*  wf = (float*)d_ws;
  uint32* wu = (uint32*)d_ws;

  // zero gcurE/gcurN/norm (words 0 .. 1087)
  hipMemsetAsync(d_ws, 0, (size_t)1088 * 4, stream);

  // CSR build: bucketize, then per-bucket LDS counting sort (both sides)
  k_bucket<<<(NP + 4095) / 4096, 256, 0, stream>>>(nidx, eidx,
                                                   wi + O_GCURE, wi + O_GCURN,
                                                   wi + O_BKTE, wi + O_BKTN);
  k_csr2<<<2 * NBK, 256, 0, stream>>>(wi + O_GCURE, wi + O_GCURN,
                                      wi + O_BKTE, wi + O_BKTN,
                                      wi + O_CSRE, wi + O_CSRN,
                                      wi + O_DEGE, wi + O_DEGN,
                                      wf + O_BINV, wf + O_DINV);

  k_compose<<<1, 256, 0, stream>>>(Wmu, bmu, dW1, db1, wf + O_C1, wf + O_C1B);
  k_cast_x<<<(NN * 32 / 8 + 255) / 256, 256, 0, stream>>>(x, wu + O_XB);

  const int G32 = (NE * 4 + 255) / 256;   // 4 lanes/row, bf16 32-wide
  const int G64 = (NE * 8 + 255) / 256;   // 8 lanes/row, bf16 64-wide
  const int GG  = NN * 16 / 256;          // row kernels, 16 lanes/row

  // layer 1 (aggregate bf16 32-wide, then GEMM+LN+leaky -> bf16 t)
  k_seg_agg<32, false><<<G32, 256, 0, stream>>>(wu + O_XB, wi + O_CSRE,
                                                wi + O_DEGE, wf + O_BINV,
                                                wu + O_HE, nullptr);
  k_seg_agg<32, true><<<G32, 256, 0, stream>>>(wu + O_HE, wi + O_CSRN,
                                               wi + O_DEGN, wf + O_DINV,
                                               nullptr, wf + O_A);
  k_gemm_ln<<<GG, 256, 0, stream>>>(wf + O_A, W1, b1, g1, be1, wu + O_T);

  // layer 2
  k_seg_agg<64, false><<<G64, 256, 0, stream>>>(wu + O_T, wi + O_CSRE,
                                                wi + O_DEGE, wf + O_BINV,
                                                wu + O_HE, nullptr);
  k_seg_agg<64, true><<<G64, 256, 0, stream>>>(wu + O_HE, wi + O_CSRN,
                                               wi + O_DEGN, wf + O_DINV,
                                               nullptr, wf + O_A);
  k_gemm_leaky<<<GG, 256, 0, stream>>>(wf + O_A, W2, b2, wu + O_T);

  // heads: one shared aggregation; logvar GEMM + mu-composed decode
  k_seg_agg<64, false><<<G64, 256, 0, stream>>>(wu + O_T, wi + O_CSRE,
                                                wi + O_DEGE, wf + O_BINV,
                                                wu + O_HE, nullptr);
  k_seg_agg<64, true><<<G64, 256, 0, stream>>>(wu + O_HE, wi + O_CSRN,
                                               wi + O_DEGN, wf + O_DINV,
                                               nullptr, wf + O_A);
  k_gemm_lv<<<GG, 256, 0, stream>>>(wf + O_A, Wlv, blv, out + 2 * NN);
  k_decode<<<(NN + 255) / 256, 256, 0, stream>>>(wf + O_A, wf + O_C1, wf + O_C1B,
                                                 dW2, db2, dW3, db3,
                                                 out, wf + O_NORM);
  k_scale<<<(2 * NN + 255) / 256, 256, 0, stream>>>(out, wf + O_NORM);
}